// Round 20
// baseline (484.796 us; speedup 1.0000x reference)
//
#include <hip/hip_runtime.h>
#include <hip/hip_bf16.h>
#include <math.h>

#define BATCH 16
#define L_SEQ 196
#define PATCH_DIM 768
#define D_MODEL 512
#define D_INNER 1024
#define D_STATE 16
#define D_CONV 4
#define DT_RANK 32
#define N_LAYERS 4
#define N_CLASSES 1000
#define ROWS (BATCH * L_SEQ)   // 3136
#define ROWSP 3200             // padded (multiple of 128)
#define NBIG 1152              // delta(1024) + bc(32), padded to 128

typedef __hip_bfloat16 bf16;
typedef __attribute__((ext_vector_type(8))) __bf16 bf16x8;
typedef __attribute__((ext_vector_type(8))) short short8;
typedef __attribute__((ext_vector_type(4))) float f32x4;

__device__ __forceinline__ void gload_lds16(const void* g, void* l) {
    __builtin_amdgcn_global_load_lds((const __attribute__((address_space(1))) void*)g,
                                     (__attribute__((address_space(3))) void*)l, 16, 0, 0);
}
__device__ __forceinline__ float bfbits2f(int b) {
    return __int_as_float(((unsigned)b & 0xFFFFu) << 16);
}
__device__ __forceinline__ unsigned short f2bfbits(float f) {
    __hip_bfloat16 h = __float2bfloat16(f);
    return *reinterpret_cast<unsigned short*>(&h);
}

// ---------------------------------------------------------------------------
// patchify: x[B,224,224,3] -> p[3136,768] bf16.  One thread = one pixel (3 ch).
__global__ __launch_bounds__(256) void patchify_kernel(
    const float* __restrict__ x, bf16* __restrict__ p)
{
    int row = blockIdx.x;
    int t = threadIdx.x;
    int b = row / L_SEQ, l = row % L_SEQ;
    int i = l / 14, j = l % 14;
    int ph = t >> 4, pw = t & 15;
    const float* src = x + (((size_t)b * 224 + i * 16 + ph) * 224 + (j * 16 + pw)) * 3;
    bf16* dst = p + (size_t)row * PATCH_DIM + t * 3;
    dst[0] = __float2bfloat16(src[0]);
    dst[1] = __float2bfloat16(src[1]);
    dst[2] = __float2bfloat16(src[2]);
}

// merged small prep: [0,392) posemb; [392,904) bcw; [904,968) cwt
__global__ void smallprep_kernel(float* __restrict__ pos,
                                 const float* __restrict__ xpw_all,
                                 bf16* __restrict__ WtBig_all,
                                 const float* __restrict__ cw,
                                 float* __restrict__ cwT) {
    int bid = blockIdx.x, tid = threadIdx.x;
    if (bid < 392) {
        int idx = bid * 256 + tid;
        if (idx >= L_SEQ * D_MODEL) return;
        int l = idx >> 9, col = idx & 511;
        int qd = col >> 7, wi = col & 127;
        float omega = powf(10000.f, -(float)wi / 127.f);
        float yv = (float)(l / 14), xv = (float)(l % 14);
        float arg = (qd < 2 ? xv : yv) * omega;
        pos[idx] = (qd & 1) ? cosf(arg) : sinf(arg);
    } else if (bid < 904) {
        int z = (bid - 392) >> 7;
        int idx = ((bid - 392) & 127) * 256 + tid;
        const float* xpw = xpw_all + (size_t)z * D_INNER * 64;
        bf16* WtBig = WtBig_all + (size_t)z * NBIG * D_INNER;
        int j = idx >> 10, k = idx & 1023;
        int src = (j & 1) ? 48 + (j >> 1) : 32 + (j >> 1);
        WtBig[(size_t)(1024 + j) * 1024 + k] = __float2bfloat16(xpw[k * 64 + src]);
    } else {
        int z = (bid - 904) >> 4;
        int idx = ((bid - 904) & 15) * 256 + tid;
        int d = idx >> 2, k = idx & 3;
        cwT[(size_t)z * 4096 + k * 1024 + d] = cw[(size_t)z * 4096 + d * 4 + k];
    }
}

// transpose-convert: src[K][N] f32 -> dst[Npad][K] bf16 (zero-fill), z = layer
__global__ __launch_bounds__(256) void transpose_bf16_kernel(
    const float* __restrict__ src, bf16* __restrict__ dst,
    int K, int N, int Npad, size_t src_lstride, size_t dst_lstride)
{
    src += (size_t)blockIdx.z * src_lstride;
    dst += (size_t)blockIdx.z * dst_lstride;
    __shared__ float tile[32][33];
    int kb = blockIdx.y * 32, nb = blockIdx.x * 32;
    int tx = threadIdx.x & 31, ty = threadIdx.x >> 5;  // 32 x 8
    #pragma unroll
    for (int i = 0; i < 4; ++i) {
        int k = kb + ty + 8 * i, n = nb + tx;
        tile[ty + 8 * i][tx] = (k < K && n < N) ? src[(size_t)k * N + n] : 0.f;
    }
    __syncthreads();
    #pragma unroll
    for (int i = 0; i < 4; ++i) {
        int n = nb + ty + 8 * i, k = kb + tx;
        if (n < Npad && k < K) dst[(size_t)n * K + k] = __float2bfloat16(tile[tx][ty + 8 * i]);
    }
}

// W_comb^T bf16: Wt[z][n][k] = sum_{r<32} dtw_z[r][n] * xpw_z[k][r]
__global__ __launch_bounds__(256) void wcomb_kernel(
    const float* __restrict__ xpw_all,   // [z][1024][64]
    const float* __restrict__ dtw_all,   // [z][32][1024]
    bf16* __restrict__ WtBig_all)        // [z][NBIG][1024]
{
    int z = blockIdx.z;
    const float* xpw = xpw_all + (size_t)z * D_INNER * 64;
    const float* dtw = dtw_all + (size_t)z * DT_RANK * D_INNER;
    bf16* Wt = WtBig_all + (size_t)z * NBIG * D_INNER;
    __shared__ float sd[32][33];  // [r][n]
    __shared__ float sx[32][33];  // [k][r]
    int n0 = blockIdx.x * 32, k0 = blockIdx.y * 32;
    int tid = threadIdx.x;
    #pragma unroll
    for (int i = 0; i < 4; ++i) {
        int e = tid + 256 * i;
        sd[e >> 5][e & 31] = dtw[(size_t)(e >> 5) * D_INNER + n0 + (e & 31)];
        sx[e >> 5][e & 31] = xpw[(size_t)(k0 + (e >> 5)) * 64 + (e & 31)];
    }
    __syncthreads();
    int ty = tid >> 4, tx = tid & 15;
    int nn = ty * 2, kk = tx * 2;
    float a00 = 0.f, a01 = 0.f, a10 = 0.f, a11 = 0.f;
    #pragma unroll
    for (int r = 0; r < 32; ++r) {
        float d0 = sd[r][nn], d1 = sd[r][nn + 1];
        float x0 = sx[kk][r], x1 = sx[kk + 1][r];
        a00 += d0 * x0; a01 += d0 * x1;
        a10 += d1 * x0; a11 += d1 * x1;
    }
    Wt[(size_t)(n0 + nn) * D_INNER + k0 + kk]           = __float2bfloat16(a00);
    Wt[(size_t)(n0 + nn) * D_INNER + k0 + kk + 1]       = __float2bfloat16(a01);
    Wt[(size_t)(n0 + nn + 1) * D_INNER + k0 + kk]       = __float2bfloat16(a10);
    Wt[(size_t)(n0 + nn + 1) * D_INNER + k0 + kk + 1]   = __float2bfloat16(a11);
}

// ---------------------------------------------------------------------------
// Unified bf16 MFMA GEMM, BN=128, BK=64, 4 waves (2Mx2N), 16x16x32 MFMA.
// BM=32/64: ring-3 LDS, depth-2 prefetch, counted vmcnt; stage issued inside
// compute phase; setprio(1) around MFMA cluster.
// MODE 0: Cb = bf16(acc); 2: +bias+pos; 3: +=
// MODE 4: col<1024 -> Cb[row*1024+col] = bf16(softplus(acc+bias[col]))  (delta)
//         1024<=col<1056 -> Cf2[row*32 + col-1024] = acc                (bc)
template<int MODE, int BM>
__global__ __launch_bounds__(256) void gemm64(
    const bf16* __restrict__ A, const bf16* __restrict__ Wt,
    int K, int gx, int Nstore, int M, int ldc,
    float* __restrict__ Cf, bf16* __restrict__ Cb,
    const float* __restrict__ bias, const float* __restrict__ pos,
    float* __restrict__ Cf2)
{
    constexpr int NBUF = 3;
    constexpr int MI = BM / 32;
    constexpr int AL = BM / 32;
    constexpr int NL = AL + 4;
    int nwg = gridDim.x, bid = blockIdx.x;
    int q = nwg >> 3, r = nwg & 7;
    int xcd = bid & 7, sub = bid >> 3;
    int wgid = (xcd < r ? xcd * (q + 1) : r * (q + 1) + (xcd - r) * q) + sub;
    int bx = wgid % gx, by = wgid / gx;
    int bm = by * BM, bn = bx * 128;

    __shared__ short Als[NBUF][BM * 64];
    __shared__ short Bls[NBUF][128 * 64];
    int tid = threadIdx.x;
    int lane = tid & 63, wid = tid >> 6;
    int wm = wid >> 1, wn = wid & 1;

    int t3 = tid >> 3, t7 = tid & 7;
    const bf16* gA[AL];
    int aOff[AL];
    #pragma unroll
    for (int i = 0; i < AL; ++i) {
        int rA = i * 32 + t3;
        int kA = t7 ^ (rA & 7);
        gA[i] = A + (size_t)(bm + rA) * K + kA * 8;
        aOff[i] = (i * 256 + wid * 64) * 8;
    }
    const bf16* gB[4];
    int bOff[4];
    #pragma unroll
    for (int i = 0; i < 4; ++i) {
        int rB = i * 32 + t3;
        int kB = t7 ^ (rB & 7);
        gB[i] = Wt + (size_t)(bn + rB) * K + kB * 8;
        bOff[i] = (i * 256 + wid * 64) * 8;
    }

    auto stage = [&](int buf, int k0) {
        #pragma unroll
        for (int i = 0; i < AL; ++i) gload_lds16(gA[i] + k0, &Als[buf][aOff[i]]);
        #pragma unroll
        for (int i = 0; i < 4; ++i) gload_lds16(gB[i] + k0, &Bls[buf][bOff[i]]);
    };

    f32x4 acc[MI][4];
    #pragma unroll
    for (int i = 0; i < MI; ++i)
        #pragma unroll
        for (int j = 0; j < 4; ++j)
            acc[i][j] = (f32x4){0.f, 0.f, 0.f, 0.f};

    int nsteps = K >> 6;
    stage(0, 0);
    if (nsteps > 1) stage(1, 64);

    for (int s = 0; s < nsteps; ++s) {
        int buf = s % 3;
        if (s + 1 < nsteps) {
            asm volatile("s_waitcnt vmcnt(%0)" :: "n"(NL) : "memory");
        } else {
            asm volatile("s_waitcnt vmcnt(0)" ::: "memory");
        }
        __builtin_amdgcn_s_barrier();
        __builtin_amdgcn_sched_barrier(0);

        bf16x8 af[2][MI], bfr[2][4];
        #pragma unroll
        for (int kw = 0; kw < 2; ++kw) {
            int kc = kw * 4 + (lane >> 4);
            #pragma unroll
            for (int mi = 0; mi < MI; ++mi) {
                int row = wm * (BM / 2) + mi * 16 + (lane & 15);
                int kbp = kc ^ (row & 7);
                af[kw][mi] = *reinterpret_cast<const bf16x8*>(&Als[buf][row * 64 + kbp * 8]);
            }
            #pragma unroll
            for (int nj = 0; nj < 4; ++nj) {
                int row = wn * 64 + nj * 16 + (lane & 15);
                int kbp = kc ^ (row & 7);
                bfr[kw][nj] = *reinterpret_cast<const bf16x8*>(&Bls[buf][row * 64 + kbp * 8]);
            }
        }
        if (s + 2 < nsteps) stage((s + 2) % 3, (s + 2) * 64);

        __builtin_amdgcn_s_setprio(1);
        #pragma unroll
        for (int kw = 0; kw < 2; ++kw)
            #pragma unroll
            for (int mi = 0; mi < MI; ++mi)
                #pragma unroll
                for (int nj = 0; nj < 4; ++nj)
                    acc[mi][nj] = __builtin_amdgcn_mfma_f32_16x16x32_bf16(af[kw][mi], bfr[kw][nj], acc[mi][nj], 0, 0, 0);
        __builtin_amdgcn_s_setprio(0);

        __builtin_amdgcn_sched_barrier(0);
        __builtin_amdgcn_s_barrier();
    }

    #pragma unroll
    for (int mi = 0; mi < MI; ++mi) {
        #pragma unroll
        for (int nj = 0; nj < 4; ++nj) {
            int r0 = bm + wm * (BM / 2) + mi * 16 + ((lane >> 4) << 2);
            int col = bn + wn * 64 + nj * 16 + (lane & 15);
            if (col >= Nstore) continue;
            #pragma unroll
            for (int j = 0; j < 4; ++j) {
                int row = r0 + j;
                if (row >= M) continue;
                float v = acc[mi][nj][j];
                if (MODE == 4) {
                    if (col < 1024) {
                        float z = v + bias[col];
                        float sp = (z > 20.f) ? z : log1pf(__expf(z));
                        Cb[(size_t)row * 1024 + col] = __float2bfloat16(sp);
                    } else {
                        Cf2[(size_t)row * 32 + (col - 1024)] = v;
                    }
                } else {
                    size_t o = (size_t)row * ldc + col;
                    if (MODE == 0) Cb[o] = __float2bfloat16(v);
                    else if (MODE == 2) Cf[o] = v + bias[col] + pos[(size_t)(row % L_SEQ) * D_MODEL + col];
                    else if (MODE == 3) Cf[o] += v;
                }
            }
        }
    }
}

// ---------------------------------------------------------------------------
// RMSNorm, wave-per-row: 4 rows/block, no barriers, shfl_xor reduce.
__global__ __launch_bounds__(256) void rmsnorm_kernel(
    const float* __restrict__ h, const float* __restrict__ w, bf16* __restrict__ o)
{
    int row = (blockIdx.x << 2) | (threadIdx.x >> 6);
    int lane = threadIdx.x & 63;
    const float* hr = h + (size_t)row * D_MODEL + lane * 8;
    f32x4 v0 = *reinterpret_cast<const f32x4*>(hr);
    f32x4 v1 = *reinterpret_cast<const f32x4*>(hr + 4);
    float ss = v0.x*v0.x + v0.y*v0.y + v0.z*v0.z + v0.w*v0.w
             + v1.x*v1.x + v1.y*v1.y + v1.z*v1.z + v1.w*v1.w;
    #pragma unroll
    for (int off = 32; off; off >>= 1) ss += __shfl_xor(ss, off);
    float sc = rsqrtf(ss * (1.f / D_MODEL) + 1e-5f);
    const float* wr = w + lane * 8;
    f32x4 w0 = *reinterpret_cast<const f32x4*>(wr);
    f32x4 w1 = *reinterpret_cast<const f32x4*>(wr + 4);
    short8 ov;
    ov[0] = (short)f2bfbits(v0.x * sc * w0.x);
    ov[1] = (short)f2bfbits(v0.y * sc * w0.y);
    ov[2] = (short)f2bfbits(v0.z * sc * w0.z);
    ov[3] = (short)f2bfbits(v0.w * sc * w0.w);
    ov[4] = (short)f2bfbits(v1.x * sc * w1.x);
    ov[5] = (short)f2bfbits(v1.y * sc * w1.y);
    ov[6] = (short)f2bfbits(v1.z * sc * w1.z);
    ov[7] = (short)f2bfbits(v1.w * sc * w1.w);
    *reinterpret_cast<short8*>(o + (size_t)row * D_MODEL + lane * 8) = ov;
}

// causal depthwise conv (k=4) + SiLU + gate precompute, vectorized x8 channels.
__global__ __launch_bounds__(256) void conv_silu_kernel(
    const bf16* __restrict__ xr, const float* __restrict__ cwT,
    bf16* __restrict__ xs, unsigned int* __restrict__ ug)
{
    int idx = blockIdx.x * 256 + threadIdx.x;
    if (idx >= ROWS * 128) return;
    int dg = idx & 127, row = idx >> 7;
    int d0 = dg << 3;
    int l = row % L_SEQ;
    float acc[8] = {0.f,0.f,0.f,0.f,0.f,0.f,0.f,0.f};
    #pragma unroll
    for (int k = 0; k < 4; ++k) {
        int ls = l - 3 + k;
        if (ls < 0) continue;
        short8 xv = *reinterpret_cast<const short8*>(xr + (size_t)(row - 3 + k) * 2048 + d0);
        const float* wk = cwT + k * 1024 + d0;
        #pragma unroll
        for (int j = 0; j < 8; ++j)
            acc[j] += bfbits2f(xv[j]) * wk[j];
    }
    short8 rv = *reinterpret_cast<const short8*>(xr + (size_t)row * 2048 + 1024 + d0);
    short8 xsv;
    unsigned ugv[8];
    #pragma unroll
    for (int j = 0; j < 8; ++j) {
        float u = acc[j] / (1.f + __expf(-acc[j]));
        unsigned short ub = f2bfbits(u);
        xsv[j] = (short)ub;
        float res = bfbits2f(rv[j]);
        float g = res / (1.f + __expf(-res));
        ugv[j] = (unsigned)ub | ((unsigned)f2bfbits(g) << 16);
    }
    *reinterpret_cast<short8*>(xs + (size_t)row * 1024 + d0) = xsv;
    uint4* up = reinterpret_cast<uint4*>(ug + (size_t)row * 1024 + d0);
    up[0] = make_uint4(ugv[0], ugv[1], ugv[2], ugv[3]);
    up[1] = make_uint4(ugv[4], ugv[5], ugv[6], ugv[7]);
}

// ---------------------------------------------------------------------------
// State-parallel scan + gate: 4 states/lane, 4 lanes/channel, 64 ch/block.
// bc rows for this batch staged in LDS (25KB): per-step B/C reads become
// conflict-free LDS broadcasts instead of global loads.
__global__ __launch_bounds__(256) void scan_sp_kernel(
    const unsigned int* __restrict__ ug,   // {u,g} bf16x2  [rows,1024]
    const unsigned short* __restrict__ dl, // delta bf16    [rows,1024]
    const float* __restrict__ bc,          // [rows,32]  {B0,C0,B1,C1,...}
    const float* __restrict__ A_log,       // [1024,16]
    const float* __restrict__ Dv,          // [1024]
    bf16* __restrict__ y)                  // [rows,1024] bf16
{
    __shared__ float bcs[L_SEQ * 32];      // 25088 B
    int tid = threadIdx.x;
    int n3 = tid & 3, ch = tid >> 2;
    int b = blockIdx.x >> 4;
    int d = (((int)blockIdx.x & 15) << 6) | ch;
    size_t bbase = (size_t)b * L_SEQ;

    // stage bc for this batch: 1568 f32x4, coalesced
    {
        const f32x4* src = reinterpret_cast<const f32x4*>(bc + bbase * 32);
        #pragma unroll
        for (int i = 0; i < 7; ++i) {
            int e = tid + i * 256;
            if (e < L_SEQ * 8)
                *reinterpret_cast<f32x4*>(&bcs[e * 4]) = src[e];
        }
    }

    const float L2E = 1.4426950408889634f;
    float A0 = -__expf(A_log[d * 16 + 4 * n3])     * L2E;
    float A1 = -__expf(A_log[d * 16 + 4 * n3 + 1]) * L2E;
    float A2 = -__expf(A_log[d * 16 + 4 * n3 + 2]) * L2E;
    float A3 = -__expf(A_log[d * 16 + 4 * n3 + 3]) * L2E;
    float Dd = Dv[d];
    float s0 = 0.f, s1 = 0.f, s2 = 0.f, s3 = 0.f;

    const unsigned* pu        = ug + bbase * 1024 + d;
    const unsigned short* pd  = dl + bbase * 1024 + d;
    bf16*           py = y + bbase * 1024 + d;
    int bo = 8 * n3;                       // LDS offset (floats)

    __syncthreads();

    unsigned uv[8];
    unsigned short dv[8];
    f32x4 bc0[8], bc1[8];

#define LOADSLOT(i) { \
    uv[i]  = pu[(i) * 1024]; \
    dv[i]  = pd[(i) * 1024]; \
    bc0[i] = *reinterpret_cast<const f32x4*>(&bcs[bo + (i) * 32]); \
    bc1[i] = *reinterpret_cast<const f32x4*>(&bcs[bo + (i) * 32 + 4]); }

#define STEP(i) { \
    float _dl = bfbits2f(dv[i]); \
    float _u  = __int_as_float(uv[i] << 16); \
    float _a0 = __builtin_amdgcn_exp2f(_dl * A0); \
    float _a1 = __builtin_amdgcn_exp2f(_dl * A1); \
    float _a2 = __builtin_amdgcn_exp2f(_dl * A2); \
    float _a3 = __builtin_amdgcn_exp2f(_dl * A3); \
    float _du = _dl * _u; \
    s0 = _a0 * s0 + _du * bc0[i].x; \
    s1 = _a1 * s1 + _du * bc0[i].z; \
    s2 = _a2 * s2 + _du * bc1[i].x; \
    s3 = _a3 * s3 + _du * bc1[i].z; \
    float _p  = s0 * bc0[i].y + s1 * bc0[i].w; \
    float _p2 = s2 * bc1[i].y + s3 * bc1[i].w; \
    _p += _p2; \
    _p += __int_as_float(__builtin_amdgcn_mov_dpp(__float_as_int(_p), 0xB1, 0xF, 0xF, true)); \
    _p += __int_as_float(__builtin_amdgcn_mov_dpp(__float_as_int(_p), 0x4E, 0xF, 0xF, true)); \
    if (n3 == 0) { \
        float _g = __int_as_float(uv[i] & 0xFFFF0000u); \
        py[(i) * 1024] = __float2bfloat16((_p + _u * Dd) * _g); \
    } }

    LOADSLOT(0) LOADSLOT(1) LOADSLOT(2) LOADSLOT(3)
    LOADSLOT(4) LOADSLOT(5) LOADSLOT(6) LOADSLOT(7)
    pu += 8 * 1024; pd += 8 * 1024; bo += 8 * 32;

    for (int g = 0; g < 23; ++g) {
        STEP(0) LOADSLOT(0)
        STEP(1) LOADSLOT(1)
        STEP(2) LOADSLOT(2)
        STEP(3) LOADSLOT(3)
        STEP(4) LOADSLOT(4)
        STEP(5) LOADSLOT(5)
        STEP(6) LOADSLOT(6)
        STEP(7) LOADSLOT(7)
        pu += 8 * 1024; pd += 8 * 1024; bo += 8 * 32; py += 8 * 1024;
    }
    STEP(0) LOADSLOT(0)
    STEP(1) LOADSLOT(1)
    STEP(2) LOADSLOT(2)
    STEP(3) LOADSLOT(3)
    STEP(4) STEP(5) STEP(6) STEP(7)
    py += 8 * 1024;
    STEP(0) STEP(1) STEP(2) STEP(3)
#undef LOADSLOT
#undef STEP
}

// ---------------------------------------------------------------------------
// two-phase mean.  Phase A: grid (8,16): block (q,b) sums rows q*25..q*25+24.
__global__ __launch_bounds__(256) void mean_part_kernel(
    const float* __restrict__ h, float* __restrict__ hmp)
{
    int q = blockIdx.x, b = blockIdx.y;
    int l0 = q * 25;
    int l1 = min(l0 + 25, L_SEQ);
    const float* hb = h + ((size_t)b * L_SEQ + l0) * D_MODEL;
    #pragma unroll
    for (int half = 0; half < 2; ++half) {
        int c = threadIdx.x + half * 256;
        float acc = 0.f;
        for (int l = l0; l < l1; ++l) {
            acc += hb[c];
            hb += D_MODEL;
        }
        hb -= (size_t)(l1 - l0) * D_MODEL;
        hmp[((size_t)b * 8 + q) * D_MODEL + c] = acc;
    }
}

// head: phase B reduce 8 partials into LDS, then out[b][c].  grid (4,16)
__global__ __launch_bounds__(256) void head_kernel(
    const float* __restrict__ hmp, const float* __restrict__ head_w,
    const float* __restrict__ head_b, float* __restrict__ out)
{
    __shared__ float hmr[D_MODEL];
    int tid = threadIdx.x;
    int b = blockIdx.y;
    const float* hp = hmp + (size_t)b * 8 * D_MODEL;
    #pragma unroll
    for (int half = 0; half < 2; ++half) {
        int c = tid + half * 256;
        float acc = 0.f;
        #pragma unroll
        for (int q = 0; q < 8; ++q) acc += hp[q * D_MODEL + c];
        hmr[c] = acc * (1.f / L_SEQ);
    }
    __syncthreads();
    int c = blockIdx.x * 256 + tid;
    if (c >= N_CLASSES) return;
    float acc = head_b[c];
    #pragma unroll 8
    for (int k = 0; k < D_MODEL; ++k)
        acc += hmr[k] * head_w[(size_t)k * N_CLASSES + c];
    out[(size_t)b * N_CLASSES + c] = acc;
}

// ---------------------------------------------------------------------------
extern "C" void kernel_launch(void* const* d_in, const int* in_sizes, int n_in,
                              void* d_out, int out_size, void* d_ws, size_t ws_size,
                              hipStream_t stream) {
    const float* x         = (const float*)d_in[0];
    const float* patch_w   = (const float*)d_in[1];
    const float* patch_b   = (const float*)d_in[2];
    const float* norm_w    = (const float*)d_in[3];
    const float* in_proj_w = (const float*)d_in[4];
    const float* conv_w    = (const float*)d_in[5];
    const float* x_proj_w  = (const float*)d_in[6];
    const float* dt_proj_w = (const float*)d_in[7];
    const float* dt_proj_b = (const float*)d_in[8];
    const float* A_log     = (const float*)d_in[9];
    const float* Dv        = (const float*)d_in[10];
    const float* out_proj_w= (const float*)d_in[11];
    const float* head_w    = (const float*)d_in[12];
    const float* head_b    = (const float*)d_in[13];
    float* out = (float*)d_out;

    char* base = (char*)d_ws;
    size_t off = 0;
    auto alloc = [&](size_t bytes) -> void* {
        void* p = base + off;
        off += (bytes + 255) & ~(size_t)255;
        return p;
    };
    float* pos   = (float*)alloc((size_t)L_SEQ * D_MODEL * 4);
    bf16*  pwT   = (bf16*) alloc((size_t)D_MODEL * PATCH_DIM * 2);
    bf16*  inT   = (bf16*) alloc((size_t)N_LAYERS * 2 * D_INNER * D_MODEL * 2);
    bf16*  WtBig = (bf16*) alloc((size_t)N_LAYERS * NBIG * D_INNER * 2);
    bf16*  opT   = (bf16*) alloc((size_t)N_LAYERS * D_MODEL * D_INNER * 2);
    float* cwT   = (float*)alloc((size_t)N_LAYERS * 4 * D_INNER * 4);
    float* h     = (float*)alloc((size_t)ROWS * D_MODEL * 4);
    bf16*  xn    = (bf16*) alloc((size_t)ROWSP * D_MODEL * 2);
    char*  reg0  = (char*) alloc((size_t)ROWSP * 2 * D_INNER * 2);
    bf16*  p     = (bf16*)reg0;
    bf16*  xr    = (bf16*)reg0;
    bf16*  xs    = (bf16*) alloc((size_t)ROWSP * D_INNER * 2);
    unsigned int* ug = (unsigned int*)alloc((size_t)ROWSP * D_INNER * 4);
    bf16*  delta = (bf16*) alloc((size_t)ROWSP * D_INNER * 2);
    float* bcb   = (float*)alloc((size_t)ROWS * 32 * 4);
    bf16*  yb    = (bf16*) alloc((size_t)ROWSP * D_INNER * 2);
    float* hmp   = (float*)alloc((size_t)BATCH * 8 * D_MODEL * 4);

    // ---- prologue + batched weight prep ----
    patchify_kernel<<<ROWS, 256, 0, stream>>>(x, p);
    smallprep_kernel<<<968, 256, 0, stream>>>(pos, x_proj_w, WtBig, conv_w, cwT);
    transpose_bf16_kernel<<<dim3(16, 24), 256, 0, stream>>>(
        patch_w, pwT, PATCH_DIM, D_MODEL, D_MODEL, 0, 0);
    transpose_bf16_kernel<<<dim3(64, 16, N_LAYERS), 256, 0, stream>>>(
        in_proj_w, inT, D_MODEL, 2 * D_INNER, 2 * D_INNER,
        (size_t)D_MODEL * 2 * D_INNER, (size_t)2 * D_INNER * D_MODEL);
    transpose_bf16_kernel<<<dim3(16, 32, N_LAYERS), 256, 0, stream>>>(
        out_proj_w, opT, D_INNER, D_MODEL, D_MODEL,
        (size_t)D_INNER * D_MODEL, (size_t)D_MODEL * D_INNER);
    wcomb_kernel<<<dim3(32, 32, N_LAYERS), 256, 0, stream>>>(
        x_proj_w, dt_proj_w, WtBig);

    // h = p @ patch_w + patch_b + pos   (BM=32, grid 400)
    gemm64<2, 32><<<(D_MODEL / 128) * (ROWSP / 32), 256, 0, stream>>>(
        p, pwT, PATCH_DIM, D_MODEL / 128, D_MODEL, ROWS, D_MODEL,
        h, nullptr, patch_b, pos, nullptr);

    for (int layer = 0; layer < N_LAYERS; ++layer) {
        rmsnorm_kernel<<<ROWS / 4, 256, 0, stream>>>(h, norm_w + layer * D_MODEL, xn);

        // xr = xn @ in_proj  [3136,2048] bf16   (BM=64, grid 800)
        gemm64<0, 64><<<(2 * D_INNER / 128) * (ROWSP / 64), 256, 0, stream>>>(
            xn, inT + (size_t)layer * 2 * D_INNER * D_MODEL,
            D_MODEL, 2 * D_INNER / 128, 2 * D_INNER, ROWS, 2 * D_INNER,
            nullptr, xr, nullptr, nullptr, nullptr);

        conv_silu_kernel<<<(ROWS * 128 + 255) / 256, 256, 0, stream>>>(
            xr, cwT + (size_t)layer * 4 * D_INNER, xs, ug);

        // delta(bf16) = softplus(xs @ W_comb + dtb); bc interleaved  (BM=64, grid 450)
        gemm64<4, 64><<<(NBIG / 128) * (ROWSP / 64), 256, 0, stream>>>(
            xs, WtBig + (size_t)layer * NBIG * D_INNER,
            D_INNER, NBIG / 128, 1056, ROWS, 0,
            nullptr, delta, dt_proj_b + (size_t)layer * D_INNER, nullptr, bcb);

        // state-parallel scan + gate -> yb bf16  (grid 256)
        scan_sp_kernel<<<BATCH * (D_INNER / 64), 256, 0, stream>>>(
            ug, (const unsigned short*)delta, bcb,
            A_log + (size_t)layer * D_INNER * D_STATE,
            Dv + (size_t)layer * D_INNER, yb);

        // h += yb @ out_proj   (BM=32, grid 400)
        gemm64<3, 32><<<(D_MODEL / 128) * (ROWSP / 32), 256, 0, stream>>>(
            yb, opT + (size_t)layer * D_MODEL * D_INNER,
            D_INNER, D_MODEL / 128, D_MODEL, ROWS, D_MODEL,
            h, nullptr, nullptr, nullptr, nullptr);
    }

    mean_part_kernel<<<dim3(8, BATCH), 256, 0, stream>>>(h, hmp);
    head_kernel<<<dim3(4, BATCH), 256, 0, stream>>>(hmp, head_w, head_b, out);
}

// Round 21
// 465.431 us; speedup vs baseline: 1.0416x; 1.0416x over previous
//
#include <hip/hip_runtime.h>
#include <hip/hip_bf16.h>
#include <math.h>

#define BATCH 16
#define L_SEQ 196
#define PATCH_DIM 768
#define D_MODEL 512
#define D_INNER 1024
#define D_STATE 16
#define D_CONV 4
#define DT_RANK 32
#define N_LAYERS 4
#define N_CLASSES 1000
#define ROWS (BATCH * L_SEQ)   // 3136
#define ROWSP 3200             // padded (multiple of 128)
#define NBIG 1152              // delta(1024) + bc(32), padded to 128

typedef __hip_bfloat16 bf16;
typedef __attribute__((ext_vector_type(8))) __bf16 bf16x8;
typedef __attribute__((ext_vector_type(8))) short short8;
typedef __attribute__((ext_vector_type(4))) float f32x4;

__device__ __forceinline__ void gload_lds16(const void* g, void* l) {
    __builtin_amdgcn_global_load_lds((const __attribute__((address_space(1))) void*)g,
                                     (__attribute__((address_space(3))) void*)l, 16, 0, 0);
}
__device__ __forceinline__ float bfbits2f(int b) {
    return __int_as_float(((unsigned)b & 0xFFFFu) << 16);
}
__device__ __forceinline__ unsigned short f2bfbits(float f) {
    __hip_bfloat16 h = __float2bfloat16(f);
    return *reinterpret_cast<unsigned short*>(&h);
}

// ---------------------------------------------------------------------------
// patchify: x[B,224,224,3] -> p[3136,768] bf16.  One thread = one pixel (3 ch).
__global__ __launch_bounds__(256) void patchify_kernel(
    const float* __restrict__ x, bf16* __restrict__ p)
{
    int row = blockIdx.x;
    int t = threadIdx.x;
    int b = row / L_SEQ, l = row % L_SEQ;
    int i = l / 14, j = l % 14;
    int ph = t >> 4, pw = t & 15;
    const float* src = x + (((size_t)b * 224 + i * 16 + ph) * 224 + (j * 16 + pw)) * 3;
    bf16* dst = p + (size_t)row * PATCH_DIM + t * 3;
    dst[0] = __float2bfloat16(src[0]);
    dst[1] = __float2bfloat16(src[1]);
    dst[2] = __float2bfloat16(src[2]);
}

// merged small prep: [0,392) posemb; [392,904) bcw; [904,968) cwt
__global__ void smallprep_kernel(float* __restrict__ pos,
                                 const float* __restrict__ xpw_all,
                                 bf16* __restrict__ WtBig_all,
                                 const float* __restrict__ cw,
                                 float* __restrict__ cwT) {
    int bid = blockIdx.x, tid = threadIdx.x;
    if (bid < 392) {
        int idx = bid * 256 + tid;
        if (idx >= L_SEQ * D_MODEL) return;
        int l = idx >> 9, col = idx & 511;
        int qd = col >> 7, wi = col & 127;
        float omega = powf(10000.f, -(float)wi / 127.f);
        float yv = (float)(l / 14), xv = (float)(l % 14);
        float arg = (qd < 2 ? xv : yv) * omega;
        pos[idx] = (qd & 1) ? cosf(arg) : sinf(arg);
    } else if (bid < 904) {
        int z = (bid - 392) >> 7;
        int idx = ((bid - 392) & 127) * 256 + tid;
        const float* xpw = xpw_all + (size_t)z * D_INNER * 64;
        bf16* WtBig = WtBig_all + (size_t)z * NBIG * D_INNER;
        int j = idx >> 10, k = idx & 1023;
        int src = (j & 1) ? 48 + (j >> 1) : 32 + (j >> 1);
        WtBig[(size_t)(1024 + j) * 1024 + k] = __float2bfloat16(xpw[k * 64 + src]);
    } else {
        int z = (bid - 904) >> 4;
        int idx = ((bid - 904) & 15) * 256 + tid;
        int d = idx >> 2, k = idx & 3;
        cwT[(size_t)z * 4096 + k * 1024 + d] = cw[(size_t)z * 4096 + d * 4 + k];
    }
}

// transpose-convert: src[K][N] f32 -> dst[Npad][K] bf16 (zero-fill), z = layer
__global__ __launch_bounds__(256) void transpose_bf16_kernel(
    const float* __restrict__ src, bf16* __restrict__ dst,
    int K, int N, int Npad, size_t src_lstride, size_t dst_lstride)
{
    src += (size_t)blockIdx.z * src_lstride;
    dst += (size_t)blockIdx.z * dst_lstride;
    __shared__ float tile[32][33];
    int kb = blockIdx.y * 32, nb = blockIdx.x * 32;
    int tx = threadIdx.x & 31, ty = threadIdx.x >> 5;  // 32 x 8
    #pragma unroll
    for (int i = 0; i < 4; ++i) {
        int k = kb + ty + 8 * i, n = nb + tx;
        tile[ty + 8 * i][tx] = (k < K && n < N) ? src[(size_t)k * N + n] : 0.f;
    }
    __syncthreads();
    #pragma unroll
    for (int i = 0; i < 4; ++i) {
        int n = nb + ty + 8 * i, k = kb + tx;
        if (n < Npad && k < K) dst[(size_t)n * K + k] = __float2bfloat16(tile[tx][ty + 8 * i]);
    }
}

// W_comb^T bf16: Wt[z][n][k] = sum_{r<32} dtw_z[r][n] * xpw_z[k][r]
__global__ __launch_bounds__(256) void wcomb_kernel(
    const float* __restrict__ xpw_all,   // [z][1024][64]
    const float* __restrict__ dtw_all,   // [z][32][1024]
    bf16* __restrict__ WtBig_all)        // [z][NBIG][1024]
{
    int z = blockIdx.z;
    const float* xpw = xpw_all + (size_t)z * D_INNER * 64;
    const float* dtw = dtw_all + (size_t)z * DT_RANK * D_INNER;
    bf16* Wt = WtBig_all + (size_t)z * NBIG * D_INNER;
    __shared__ float sd[32][33];  // [r][n]
    __shared__ float sx[32][33];  // [k][r]
    int n0 = blockIdx.x * 32, k0 = blockIdx.y * 32;
    int tid = threadIdx.x;
    #pragma unroll
    for (int i = 0; i < 4; ++i) {
        int e = tid + 256 * i;
        sd[e >> 5][e & 31] = dtw[(size_t)(e >> 5) * D_INNER + n0 + (e & 31)];
        sx[e >> 5][e & 31] = xpw[(size_t)(k0 + (e >> 5)) * 64 + (e & 31)];
    }
    __syncthreads();
    int ty = tid >> 4, tx = tid & 15;
    int nn = ty * 2, kk = tx * 2;
    float a00 = 0.f, a01 = 0.f, a10 = 0.f, a11 = 0.f;
    #pragma unroll
    for (int r = 0; r < 32; ++r) {
        float d0 = sd[r][nn], d1 = sd[r][nn + 1];
        float x0 = sx[kk][r], x1 = sx[kk + 1][r];
        a00 += d0 * x0; a01 += d0 * x1;
        a10 += d1 * x0; a11 += d1 * x1;
    }
    Wt[(size_t)(n0 + nn) * D_INNER + k0 + kk]           = __float2bfloat16(a00);
    Wt[(size_t)(n0 + nn) * D_INNER + k0 + kk + 1]       = __float2bfloat16(a01);
    Wt[(size_t)(n0 + nn + 1) * D_INNER + k0 + kk]       = __float2bfloat16(a10);
    Wt[(size_t)(n0 + nn + 1) * D_INNER + k0 + kk + 1]   = __float2bfloat16(a11);
}

// ---------------------------------------------------------------------------
// Unified bf16 MFMA GEMM, BN=128, BK=64, 4 waves (2Mx2N), 16x16x32 MFMA.
// BM=32/64: ring-3 LDS, depth-2 prefetch, counted vmcnt; stage issued inside
// compute phase; setprio(1) around MFMA cluster.
// MODE 0: Cb = bf16(acc); 2: +bias+pos; 3: +=
// MODE 4: col<1024 -> Cb[row*1024+col] = bf16(softplus(acc+bias[col]))  (delta)
//         1024<=col<1056 -> Cf2[row*32 + col-1024] = acc                (bc)
template<int MODE, int BM>
__global__ __launch_bounds__(256) void gemm64(
    const bf16* __restrict__ A, const bf16* __restrict__ Wt,
    int K, int gx, int Nstore, int M, int ldc,
    float* __restrict__ Cf, bf16* __restrict__ Cb,
    const float* __restrict__ bias, const float* __restrict__ pos,
    float* __restrict__ Cf2)
{
    constexpr int NBUF = 3;
    constexpr int MI = BM / 32;
    constexpr int AL = BM / 32;
    constexpr int NL = AL + 4;
    int nwg = gridDim.x, bid = blockIdx.x;
    int q = nwg >> 3, r = nwg & 7;
    int xcd = bid & 7, sub = bid >> 3;
    int wgid = (xcd < r ? xcd * (q + 1) : r * (q + 1) + (xcd - r) * q) + sub;
    int bx = wgid % gx, by = wgid / gx;
    int bm = by * BM, bn = bx * 128;

    __shared__ short Als[NBUF][BM * 64];
    __shared__ short Bls[NBUF][128 * 64];
    int tid = threadIdx.x;
    int lane = tid & 63, wid = tid >> 6;
    int wm = wid >> 1, wn = wid & 1;

    int t3 = tid >> 3, t7 = tid & 7;
    const bf16* gA[AL];
    int aOff[AL];
    #pragma unroll
    for (int i = 0; i < AL; ++i) {
        int rA = i * 32 + t3;
        int kA = t7 ^ (rA & 7);
        gA[i] = A + (size_t)(bm + rA) * K + kA * 8;
        aOff[i] = (i * 256 + wid * 64) * 8;
    }
    const bf16* gB[4];
    int bOff[4];
    #pragma unroll
    for (int i = 0; i < 4; ++i) {
        int rB = i * 32 + t3;
        int kB = t7 ^ (rB & 7);
        gB[i] = Wt + (size_t)(bn + rB) * K + kB * 8;
        bOff[i] = (i * 256 + wid * 64) * 8;
    }

    auto stage = [&](int buf, int k0) {
        #pragma unroll
        for (int i = 0; i < AL; ++i) gload_lds16(gA[i] + k0, &Als[buf][aOff[i]]);
        #pragma unroll
        for (int i = 0; i < 4; ++i) gload_lds16(gB[i] + k0, &Bls[buf][bOff[i]]);
    };

    f32x4 acc[MI][4];
    #pragma unroll
    for (int i = 0; i < MI; ++i)
        #pragma unroll
        for (int j = 0; j < 4; ++j)
            acc[i][j] = (f32x4){0.f, 0.f, 0.f, 0.f};

    int nsteps = K >> 6;
    stage(0, 0);
    if (nsteps > 1) stage(1, 64);

    for (int s = 0; s < nsteps; ++s) {
        int buf = s % 3;
        if (s + 1 < nsteps) {
            asm volatile("s_waitcnt vmcnt(%0)" :: "n"(NL) : "memory");
        } else {
            asm volatile("s_waitcnt vmcnt(0)" ::: "memory");
        }
        __builtin_amdgcn_s_barrier();
        __builtin_amdgcn_sched_barrier(0);

        bf16x8 af[2][MI], bfr[2][4];
        #pragma unroll
        for (int kw = 0; kw < 2; ++kw) {
            int kc = kw * 4 + (lane >> 4);
            #pragma unroll
            for (int mi = 0; mi < MI; ++mi) {
                int row = wm * (BM / 2) + mi * 16 + (lane & 15);
                int kbp = kc ^ (row & 7);
                af[kw][mi] = *reinterpret_cast<const bf16x8*>(&Als[buf][row * 64 + kbp * 8]);
            }
            #pragma unroll
            for (int nj = 0; nj < 4; ++nj) {
                int row = wn * 64 + nj * 16 + (lane & 15);
                int kbp = kc ^ (row & 7);
                bfr[kw][nj] = *reinterpret_cast<const bf16x8*>(&Bls[buf][row * 64 + kbp * 8]);
            }
        }
        if (s + 2 < nsteps) stage((s + 2) % 3, (s + 2) * 64);

        __builtin_amdgcn_s_setprio(1);
        #pragma unroll
        for (int kw = 0; kw < 2; ++kw)
            #pragma unroll
            for (int mi = 0; mi < MI; ++mi)
                #pragma unroll
                for (int nj = 0; nj < 4; ++nj)
                    acc[mi][nj] = __builtin_amdgcn_mfma_f32_16x16x32_bf16(af[kw][mi], bfr[kw][nj], acc[mi][nj], 0, 0, 0);
        __builtin_amdgcn_s_setprio(0);

        __builtin_amdgcn_sched_barrier(0);
        __builtin_amdgcn_s_barrier();
    }

    #pragma unroll
    for (int mi = 0; mi < MI; ++mi) {
        #pragma unroll
        for (int nj = 0; nj < 4; ++nj) {
            int r0 = bm + wm * (BM / 2) + mi * 16 + ((lane >> 4) << 2);
            int col = bn + wn * 64 + nj * 16 + (lane & 15);
            if (col >= Nstore) continue;
            #pragma unroll
            for (int j = 0; j < 4; ++j) {
                int row = r0 + j;
                if (row >= M) continue;
                float v = acc[mi][nj][j];
                if (MODE == 4) {
                    if (col < 1024) {
                        float z = v + bias[col];
                        float sp = (z > 20.f) ? z : log1pf(__expf(z));
                        Cb[(size_t)row * 1024 + col] = __float2bfloat16(sp);
                    } else {
                        Cf2[(size_t)row * 32 + (col - 1024)] = v;
                    }
                } else {
                    size_t o = (size_t)row * ldc + col;
                    if (MODE == 0) Cb[o] = __float2bfloat16(v);
                    else if (MODE == 2) Cf[o] = v + bias[col] + pos[(size_t)(row % L_SEQ) * D_MODEL + col];
                    else if (MODE == 3) Cf[o] += v;
                }
            }
        }
    }
}

// ---------------------------------------------------------------------------
// RMSNorm, wave-per-row: 4 rows/block, no barriers, shfl_xor reduce.
__global__ __launch_bounds__(256) void rmsnorm_kernel(
    const float* __restrict__ h, const float* __restrict__ w, bf16* __restrict__ o)
{
    int row = (blockIdx.x << 2) | (threadIdx.x >> 6);
    int lane = threadIdx.x & 63;
    const float* hr = h + (size_t)row * D_MODEL + lane * 8;
    f32x4 v0 = *reinterpret_cast<const f32x4*>(hr);
    f32x4 v1 = *reinterpret_cast<const f32x4*>(hr + 4);
    float ss = v0.x*v0.x + v0.y*v0.y + v0.z*v0.z + v0.w*v0.w
             + v1.x*v1.x + v1.y*v1.y + v1.z*v1.z + v1.w*v1.w;
    #pragma unroll
    for (int off = 32; off; off >>= 1) ss += __shfl_xor(ss, off);
    float sc = rsqrtf(ss * (1.f / D_MODEL) + 1e-5f);
    const float* wr = w + lane * 8;
    f32x4 w0 = *reinterpret_cast<const f32x4*>(wr);
    f32x4 w1 = *reinterpret_cast<const f32x4*>(wr + 4);
    short8 ov;
    ov[0] = (short)f2bfbits(v0.x * sc * w0.x);
    ov[1] = (short)f2bfbits(v0.y * sc * w0.y);
    ov[2] = (short)f2bfbits(v0.z * sc * w0.z);
    ov[3] = (short)f2bfbits(v0.w * sc * w0.w);
    ov[4] = (short)f2bfbits(v1.x * sc * w1.x);
    ov[5] = (short)f2bfbits(v1.y * sc * w1.y);
    ov[6] = (short)f2bfbits(v1.z * sc * w1.z);
    ov[7] = (short)f2bfbits(v1.w * sc * w1.w);
    *reinterpret_cast<short8*>(o + (size_t)row * D_MODEL + lane * 8) = ov;
}

// causal depthwise conv (k=4) + SiLU + gate precompute, vectorized x8 channels.
__global__ __launch_bounds__(256) void conv_silu_kernel(
    const bf16* __restrict__ xr, const float* __restrict__ cwT,
    bf16* __restrict__ xs, unsigned int* __restrict__ ug)
{
    int idx = blockIdx.x * 256 + threadIdx.x;
    if (idx >= ROWS * 128) return;
    int dg = idx & 127, row = idx >> 7;
    int d0 = dg << 3;
    int l = row % L_SEQ;
    float acc[8] = {0.f,0.f,0.f,0.f,0.f,0.f,0.f,0.f};
    #pragma unroll
    for (int k = 0; k < 4; ++k) {
        int ls = l - 3 + k;
        if (ls < 0) continue;
        short8 xv = *reinterpret_cast<const short8*>(xr + (size_t)(row - 3 + k) * 2048 + d0);
        const float* wk = cwT + k * 1024 + d0;
        #pragma unroll
        for (int j = 0; j < 8; ++j)
            acc[j] += bfbits2f(xv[j]) * wk[j];
    }
    short8 rv = *reinterpret_cast<const short8*>(xr + (size_t)row * 2048 + 1024 + d0);
    short8 xsv;
    unsigned ugv[8];
    #pragma unroll
    for (int j = 0; j < 8; ++j) {
        float u = acc[j] / (1.f + __expf(-acc[j]));
        unsigned short ub = f2bfbits(u);
        xsv[j] = (short)ub;
        float res = bfbits2f(rv[j]);
        float g = res / (1.f + __expf(-res));
        ugv[j] = (unsigned)ub | ((unsigned)f2bfbits(g) << 16);
    }
    *reinterpret_cast<short8*>(xs + (size_t)row * 1024 + d0) = xsv;
    uint4* up = reinterpret_cast<uint4*>(ug + (size_t)row * 1024 + d0);
    up[0] = make_uint4(ugv[0], ugv[1], ugv[2], ugv[3]);
    up[1] = make_uint4(ugv[4], ugv[5], ugv[6], ugv[7]);
}

// ---------------------------------------------------------------------------
// State-parallel scan + gate: 4 states/lane, 4 lanes/channel, 64 ch/block.
__global__ __launch_bounds__(256) void scan_sp_kernel(
    const unsigned int* __restrict__ ug,   // {u,g} bf16x2  [rows,1024]
    const unsigned short* __restrict__ dl, // delta bf16    [rows,1024]
    const float* __restrict__ bc,          // [rows,32]  {B0,C0,B1,C1,...}
    const float* __restrict__ A_log,       // [1024,16]
    const float* __restrict__ Dv,          // [1024]
    bf16* __restrict__ y)                  // [rows,1024] bf16
{
    int tid = threadIdx.x;
    int n3 = tid & 3, ch = tid >> 2;
    int b = blockIdx.x >> 4;
    int d = (((int)blockIdx.x & 15) << 6) | ch;
    size_t bbase = (size_t)b * L_SEQ;

    const float L2E = 1.4426950408889634f;
    float A0 = -__expf(A_log[d * 16 + 4 * n3])     * L2E;
    float A1 = -__expf(A_log[d * 16 + 4 * n3 + 1]) * L2E;
    float A2 = -__expf(A_log[d * 16 + 4 * n3 + 2]) * L2E;
    float A3 = -__expf(A_log[d * 16 + 4 * n3 + 3]) * L2E;
    float Dd = Dv[d];
    float s0 = 0.f, s1 = 0.f, s2 = 0.f, s3 = 0.f;

    const unsigned* pu        = ug + bbase * 1024 + d;
    const unsigned short* pd  = dl + bbase * 1024 + d;
    const float*    pb = bc + bbase * 32 + 8 * n3;
    bf16*           py = y + bbase * 1024 + d;

    unsigned uv[8];
    unsigned short dv[8];
    f32x4 bc0[8], bc1[8];

#define LOADSLOT(i) { \
    uv[i]  = pu[(i) * 1024]; \
    dv[i]  = pd[(i) * 1024]; \
    bc0[i] = *reinterpret_cast<const f32x4*>(pb + (i) * 32); \
    bc1[i] = *reinterpret_cast<const f32x4*>(pb + (i) * 32 + 4); }

#define STEP(i) { \
    float _dl = bfbits2f(dv[i]); \
    float _u  = __int_as_float(uv[i] << 16); \
    float _a0 = __builtin_amdgcn_exp2f(_dl * A0); \
    float _a1 = __builtin_amdgcn_exp2f(_dl * A1); \
    float _a2 = __builtin_amdgcn_exp2f(_dl * A2); \
    float _a3 = __builtin_amdgcn_exp2f(_dl * A3); \
    float _du = _dl * _u; \
    s0 = _a0 * s0 + _du * bc0[i].x; \
    s1 = _a1 * s1 + _du * bc0[i].z; \
    s2 = _a2 * s2 + _du * bc1[i].x; \
    s3 = _a3 * s3 + _du * bc1[i].z; \
    float _p  = s0 * bc0[i].y + s1 * bc0[i].w; \
    float _p2 = s2 * bc1[i].y + s3 * bc1[i].w; \
    _p += _p2; \
    _p += __int_as_float(__builtin_amdgcn_mov_dpp(__float_as_int(_p), 0xB1, 0xF, 0xF, true)); \
    _p += __int_as_float(__builtin_amdgcn_mov_dpp(__float_as_int(_p), 0x4E, 0xF, 0xF, true)); \
    if (n3 == 0) { \
        float _g = __int_as_float(uv[i] & 0xFFFF0000u); \
        py[(i) * 1024] = __float2bfloat16((_p + _u * Dd) * _g); \
    } }

    LOADSLOT(0) LOADSLOT(1) LOADSLOT(2) LOADSLOT(3)
    LOADSLOT(4) LOADSLOT(5) LOADSLOT(6) LOADSLOT(7)
    pu += 8 * 1024; pd += 8 * 1024; pb += 8 * 32;

    for (int g = 0; g < 23; ++g) {
        STEP(0) LOADSLOT(0)
        STEP(1) LOADSLOT(1)
        STEP(2) LOADSLOT(2)
        STEP(3) LOADSLOT(3)
        STEP(4) LOADSLOT(4)
        STEP(5) LOADSLOT(5)
        STEP(6) LOADSLOT(6)
        STEP(7) LOADSLOT(7)
        pu += 8 * 1024; pd += 8 * 1024; pb += 8 * 32; py += 8 * 1024;
    }
    STEP(0) LOADSLOT(0)
    STEP(1) LOADSLOT(1)
    STEP(2) LOADSLOT(2)
    STEP(3) LOADSLOT(3)
    STEP(4) STEP(5) STEP(6) STEP(7)
    py += 8 * 1024;
    STEP(0) STEP(1) STEP(2) STEP(3)
#undef LOADSLOT
#undef STEP
}

// ---------------------------------------------------------------------------
// two-phase mean.  Phase A: grid (8,16): block (q,b) sums rows q*25..q*25+24.
__global__ __launch_bounds__(256) void mean_part_kernel(
    const float* __restrict__ h, float* __restrict__ hmp)
{
    int q = blockIdx.x, b = blockIdx.y;
    int l0 = q * 25;
    int l1 = min(l0 + 25, L_SEQ);
    const float* hb = h + ((size_t)b * L_SEQ + l0) * D_MODEL;
    #pragma unroll
    for (int half = 0; half < 2; ++half) {
        int c = threadIdx.x + half * 256;
        float acc = 0.f;
        for (int l = l0; l < l1; ++l) {
            acc += hb[c];
            hb += D_MODEL;
        }
        hb -= (size_t)(l1 - l0) * D_MODEL;
        hmp[((size_t)b * 8 + q) * D_MODEL + c] = acc;
    }
}

// head: phase B reduce 8 partials into LDS, then out[b][c].  grid (4,16)
__global__ __launch_bounds__(256) void head_kernel(
    const float* __restrict__ hmp, const float* __restrict__ head_w,
    const float* __restrict__ head_b, float* __restrict__ out)
{
    __shared__ float hmr[D_MODEL];
    int tid = threadIdx.x;
    int b = blockIdx.y;
    const float* hp = hmp + (size_t)b * 8 * D_MODEL;
    #pragma unroll
    for (int half = 0; half < 2; ++half) {
        int c = tid + half * 256;
        float acc = 0.f;
        #pragma unroll
        for (int q = 0; q < 8; ++q) acc += hp[q * D_MODEL + c];
        hmr[c] = acc * (1.f / L_SEQ);
    }
    __syncthreads();
    int c = blockIdx.x * 256 + tid;
    if (c >= N_CLASSES) return;
    float acc = head_b[c];
    #pragma unroll 8
    for (int k = 0; k < D_MODEL; ++k)
        acc += hmr[k] * head_w[(size_t)k * N_CLASSES + c];
    out[(size_t)b * N_CLASSES + c] = acc;
}

// ---------------------------------------------------------------------------
extern "C" void kernel_launch(void* const* d_in, const int* in_sizes, int n_in,
                              void* d_out, int out_size, void* d_ws, size_t ws_size,
                              hipStream_t stream) {
    const float* x         = (const float*)d_in[0];
    const float* patch_w   = (const float*)d_in[1];
    const float* patch_b   = (const float*)d_in[2];
    const float* norm_w    = (const float*)d_in[3];
    const float* in_proj_w = (const float*)d_in[4];
    const float* conv_w    = (const float*)d_in[5];
    const float* x_proj_w  = (const float*)d_in[6];
    const float* dt_proj_w = (const float*)d_in[7];
    const float* dt_proj_b = (const float*)d_in[8];
    const float* A_log     = (const float*)d_in[9];
    const float* Dv        = (const float*)d_in[10];
    const float* out_proj_w= (const float*)d_in[11];
    const float* head_w    = (const float*)d_in[12];
    const float* head_b    = (const float*)d_in[13];
    float* out = (float*)d_out;

    char* base = (char*)d_ws;
    size_t off = 0;
    auto alloc = [&](size_t bytes) -> void* {
        void* p = base + off;
        off += (bytes + 255) & ~(size_t)255;
        return p;
    };
    float* pos   = (float*)alloc((size_t)L_SEQ * D_MODEL * 4);
    bf16*  pwT   = (bf16*) alloc((size_t)D_MODEL * PATCH_DIM * 2);
    bf16*  inT   = (bf16*) alloc((size_t)N_LAYERS * 2 * D_INNER * D_MODEL * 2);
    bf16*  WtBig = (bf16*) alloc((size_t)N_LAYERS * NBIG * D_INNER * 2);
    bf16*  opT   = (bf16*) alloc((size_t)N_LAYERS * D_MODEL * D_INNER * 2);
    float* cwT   = (float*)alloc((size_t)N_LAYERS * 4 * D_INNER * 4);
    float* h     = (float*)alloc((size_t)ROWS * D_MODEL * 4);
    bf16*  xn    = (bf16*) alloc((size_t)ROWSP * D_MODEL * 2);
    char*  reg0  = (char*) alloc((size_t)ROWSP * 2 * D_INNER * 2);
    bf16*  p     = (bf16*)reg0;
    bf16*  xr    = (bf16*)reg0;
    bf16*  xs    = (bf16*) alloc((size_t)ROWSP * D_INNER * 2);
    unsigned int* ug = (unsigned int*)alloc((size_t)ROWSP * D_INNER * 4);
    bf16*  delta = (bf16*) alloc((size_t)ROWSP * D_INNER * 2);
    float* bcb   = (float*)alloc((size_t)ROWS * 32 * 4);
    bf16*  yb    = (bf16*) alloc((size_t)ROWSP * D_INNER * 2);
    float* hmp   = (float*)alloc((size_t)BATCH * 8 * D_MODEL * 4);

    // ---- prologue + batched weight prep ----
    patchify_kernel<<<ROWS, 256, 0, stream>>>(x, p);
    smallprep_kernel<<<968, 256, 0, stream>>>(pos, x_proj_w, WtBig, conv_w, cwT);
    transpose_bf16_kernel<<<dim3(16, 24), 256, 0, stream>>>(
        patch_w, pwT, PATCH_DIM, D_MODEL, D_MODEL, 0, 0);
    transpose_bf16_kernel<<<dim3(64, 16, N_LAYERS), 256, 0, stream>>>(
        in_proj_w, inT, D_MODEL, 2 * D_INNER, 2 * D_INNER,
        (size_t)D_MODEL * 2 * D_INNER, (size_t)2 * D_INNER * D_MODEL);
    transpose_bf16_kernel<<<dim3(16, 32, N_LAYERS), 256, 0, stream>>>(
        out_proj_w, opT, D_INNER, D_MODEL, D_MODEL,
        (size_t)D_INNER * D_MODEL, (size_t)D_MODEL * D_INNER);
    wcomb_kernel<<<dim3(32, 32, N_LAYERS), 256, 0, stream>>>(
        x_proj_w, dt_proj_w, WtBig);

    // h = p @ patch_w + patch_b + pos   (BM=32, grid 400)
    gemm64<2, 32><<<(D_MODEL / 128) * (ROWSP / 32), 256, 0, stream>>>(
        p, pwT, PATCH_DIM, D_MODEL / 128, D_MODEL, ROWS, D_MODEL,
        h, nullptr, patch_b, pos, nullptr);

    for (int layer = 0; layer < N_LAYERS; ++layer) {
        rmsnorm_kernel<<<ROWS / 4, 256, 0, stream>>>(h, norm_w + layer * D_MODEL, xn);

        // xr = xn @ in_proj  [3136,2048] bf16   (BM=64, grid 800)
        gemm64<0, 64><<<(2 * D_INNER / 128) * (ROWSP / 64), 256, 0, stream>>>(
            xn, inT + (size_t)layer * 2 * D_INNER * D_MODEL,
            D_MODEL, 2 * D_INNER / 128, 2 * D_INNER, ROWS, 2 * D_INNER,
            nullptr, xr, nullptr, nullptr, nullptr);

        conv_silu_kernel<<<(ROWS * 128 + 255) / 256, 256, 0, stream>>>(
            xr, cwT + (size_t)layer * 4 * D_INNER, xs, ug);

        // delta(bf16) = softplus(xs @ W_comb + dtb); bc interleaved  (BM=64, grid 450)
        gemm64<4, 64><<<(NBIG / 128) * (ROWSP / 64), 256, 0, stream>>>(
            xs, WtBig + (size_t)layer * NBIG * D_INNER,
            D_INNER, NBIG / 128, 1056, ROWS, 0,
            nullptr, delta, dt_proj_b + (size_t)layer * D_INNER, nullptr, bcb);

        // state-parallel scan + gate -> yb bf16  (grid 256)
        scan_sp_kernel<<<BATCH * (D_INNER / 64), 256, 0, stream>>>(
            ug, (const unsigned short*)delta, bcb,
            A_log + (size_t)layer * D_INNER * D_STATE,
            Dv + (size_t)layer * D_INNER, yb);

        // h += yb @ out_proj   (BM=32, grid 400)
        gemm64<3, 32><<<(D_MODEL / 128) * (ROWSP / 32), 256, 0, stream>>>(
            yb, opT + (size_t)layer * D_MODEL * D_INNER,
            D_INNER, D_MODEL / 128, D_MODEL, ROWS, D_MODEL,
            h, nullptr, nullptr, nullptr, nullptr);
    }

    mean_part_kernel<<<dim3(8, BATCH), 256, 0, stream>>>(h, hmp);
    head_kernel<<<dim3(4, BATCH), 256, 0, stream>>>(hmp, head_w, head_b, out);
}

// Round 22
// 460.048 us; speedup vs baseline: 1.0538x; 1.0117x over previous
//
#include <hip/hip_runtime.h>
#include <hip/hip_bf16.h>
#include <math.h>

#define BATCH 16
#define L_SEQ 196
#define PATCH_DIM 768
#define D_MODEL 512
#define D_INNER 1024
#define D_STATE 16
#define D_CONV 4
#define DT_RANK 32
#define N_LAYERS 4
#define N_CLASSES 1000
#define ROWS (BATCH * L_SEQ)   // 3136
#define ROWSP 3200             // padded (multiple of 128)
#define NBIG 1152              // delta(1024) + bc(32), padded to 128

typedef __hip_bfloat16 bf16;
typedef __attribute__((ext_vector_type(8))) __bf16 bf16x8;
typedef __attribute__((ext_vector_type(8))) short short8;
typedef __attribute__((ext_vector_type(4))) float f32x4;

__device__ __forceinline__ void gload_lds16(const void* g, void* l) {
    __builtin_amdgcn_global_load_lds((const __attribute__((address_space(1))) void*)g,
                                     (__attribute__((address_space(3))) void*)l, 16, 0, 0);
}
__device__ __forceinline__ float bfbits2f(int b) {
    return __int_as_float(((unsigned)b & 0xFFFFu) << 16);
}
__device__ __forceinline__ unsigned short f2bfbits(float f) {
    __hip_bfloat16 h = __float2bfloat16(f);
    return *reinterpret_cast<unsigned short*>(&h);
}

// ---------------------------------------------------------------------------
// patchify: x[B,224,224,3] -> p[3136,768] bf16.  One thread = one pixel (3 ch).
__global__ __launch_bounds__(256) void patchify_kernel(
    const float* __restrict__ x, bf16* __restrict__ p)
{
    int row = blockIdx.x;
    int t = threadIdx.x;
    int b = row / L_SEQ, l = row % L_SEQ;
    int i = l / 14, j = l % 14;
    int ph = t >> 4, pw = t & 15;
    const float* src = x + (((size_t)b * 224 + i * 16 + ph) * 224 + (j * 16 + pw)) * 3;
    bf16* dst = p + (size_t)row * PATCH_DIM + t * 3;
    dst[0] = __float2bfloat16(src[0]);
    dst[1] = __float2bfloat16(src[1]);
    dst[2] = __float2bfloat16(src[2]);
}

// merged small prep: [0,392) posemb; [392,904) bcw; [904,968) cwt
__global__ void smallprep_kernel(float* __restrict__ pos,
                                 const float* __restrict__ xpw_all,
                                 bf16* __restrict__ WtBig_all,
                                 const float* __restrict__ cw,
                                 float* __restrict__ cwT) {
    int bid = blockIdx.x, tid = threadIdx.x;
    if (bid < 392) {
        int idx = bid * 256 + tid;
        if (idx >= L_SEQ * D_MODEL) return;
        int l = idx >> 9, col = idx & 511;
        int qd = col >> 7, wi = col & 127;
        float omega = powf(10000.f, -(float)wi / 127.f);
        float yv = (float)(l / 14), xv = (float)(l % 14);
        float arg = (qd < 2 ? xv : yv) * omega;
        pos[idx] = (qd & 1) ? cosf(arg) : sinf(arg);
    } else if (bid < 904) {
        int z = (bid - 392) >> 7;
        int idx = ((bid - 392) & 127) * 256 + tid;
        const float* xpw = xpw_all + (size_t)z * D_INNER * 64;
        bf16* WtBig = WtBig_all + (size_t)z * NBIG * D_INNER;
        int j = idx >> 10, k = idx & 1023;
        int src = (j & 1) ? 48 + (j >> 1) : 32 + (j >> 1);
        WtBig[(size_t)(1024 + j) * 1024 + k] = __float2bfloat16(xpw[k * 64 + src]);
    } else {
        int z = (bid - 904) >> 4;
        int idx = ((bid - 904) & 15) * 256 + tid;
        int d = idx >> 2, k = idx & 3;
        cwT[(size_t)z * 4096 + k * 1024 + d] = cw[(size_t)z * 4096 + d * 4 + k];
    }
}

// transpose-convert: src[K][N] f32 -> dst[Npad][K] bf16 (zero-fill), z = layer
__global__ __launch_bounds__(256) void transpose_bf16_kernel(
    const float* __restrict__ src, bf16* __restrict__ dst,
    int K, int N, int Npad, size_t src_lstride, size_t dst_lstride)
{
    src += (size_t)blockIdx.z * src_lstride;
    dst += (size_t)blockIdx.z * dst_lstride;
    __shared__ float tile[32][33];
    int kb = blockIdx.y * 32, nb = blockIdx.x * 32;
    int tx = threadIdx.x & 31, ty = threadIdx.x >> 5;  // 32 x 8
    #pragma unroll
    for (int i = 0; i < 4; ++i) {
        int k = kb + ty + 8 * i, n = nb + tx;
        tile[ty + 8 * i][tx] = (k < K && n < N) ? src[(size_t)k * N + n] : 0.f;
    }
    __syncthreads();
    #pragma unroll
    for (int i = 0; i < 4; ++i) {
        int n = nb + ty + 8 * i, k = kb + tx;
        if (n < Npad && k < K) dst[(size_t)n * K + k] = __float2bfloat16(tile[tx][ty + 8 * i]);
    }
}

// W_comb^T bf16: Wt[z][n][k] = sum_{r<32} dtw_z[r][n] * xpw_z[k][r]
__global__ __launch_bounds__(256) void wcomb_kernel(
    const float* __restrict__ xpw_all,   // [z][1024][64]
    const float* __restrict__ dtw_all,   // [z][32][1024]
    bf16* __restrict__ WtBig_all)        // [z][NBIG][1024]
{
    int z = blockIdx.z;
    const float* xpw = xpw_all + (size_t)z * D_INNER * 64;
    const float* dtw = dtw_all + (size_t)z * DT_RANK * D_INNER;
    bf16* Wt = WtBig_all + (size_t)z * NBIG * D_INNER;
    __shared__ float sd[32][33];  // [r][n]
    __shared__ float sx[32][33];  // [k][r]
    int n0 = blockIdx.x * 32, k0 = blockIdx.y * 32;
    int tid = threadIdx.x;
    #pragma unroll
    for (int i = 0; i < 4; ++i) {
        int e = tid + 256 * i;
        sd[e >> 5][e & 31] = dtw[(size_t)(e >> 5) * D_INNER + n0 + (e & 31)];
        sx[e >> 5][e & 31] = xpw[(size_t)(k0 + (e >> 5)) * 64 + (e & 31)];
    }
    __syncthreads();
    int ty = tid >> 4, tx = tid & 15;
    int nn = ty * 2, kk = tx * 2;
    float a00 = 0.f, a01 = 0.f, a10 = 0.f, a11 = 0.f;
    #pragma unroll
    for (int r = 0; r < 32; ++r) {
        float d0 = sd[r][nn], d1 = sd[r][nn + 1];
        float x0 = sx[kk][r], x1 = sx[kk + 1][r];
        a00 += d0 * x0; a01 += d0 * x1;
        a10 += d1 * x0; a11 += d1 * x1;
    }
    Wt[(size_t)(n0 + nn) * D_INNER + k0 + kk]           = __float2bfloat16(a00);
    Wt[(size_t)(n0 + nn) * D_INNER + k0 + kk + 1]       = __float2bfloat16(a01);
    Wt[(size_t)(n0 + nn + 1) * D_INNER + k0 + kk]       = __float2bfloat16(a10);
    Wt[(size_t)(n0 + nn + 1) * D_INNER + k0 + kk + 1]   = __float2bfloat16(a11);
}

// ---------------------------------------------------------------------------
// Unified bf16 MFMA GEMM, BN=128, BK=64, 4 waves (2Mx2N), 16x16x32 MFMA.
// BM=32/64: ring-3 LDS, depth-2 prefetch, counted vmcnt; stage issued inside
// compute phase; setprio(1) around MFMA cluster.
// MODE 0: Cb = bf16(acc)
// MODE 2: Cb = bf16(acc + bias + pos)          (h residual, bf16)
// MODE 3: Cb = bf16(bf2f(Cb) + acc)            (h += ..., bf16 RMW)
// MODE 4: col<1024 -> Cb = bf16(softplus(acc+bias))  (delta)
//         1024<=col<1056 -> Cf2[row*32 + col-1024] = acc  (bc)
template<int MODE, int BM>
__global__ __launch_bounds__(256) void gemm64(
    const bf16* __restrict__ A, const bf16* __restrict__ Wt,
    int K, int gx, int Nstore, int M, int ldc,
    float* __restrict__ Cf, bf16* __restrict__ Cb,
    const float* __restrict__ bias, const float* __restrict__ pos,
    float* __restrict__ Cf2)
{
    constexpr int NBUF = 3;
    constexpr int MI = BM / 32;
    constexpr int AL = BM / 32;
    constexpr int NL = AL + 4;
    int nwg = gridDim.x, bid = blockIdx.x;
    int q = nwg >> 3, r = nwg & 7;
    int xcd = bid & 7, sub = bid >> 3;
    int wgid = (xcd < r ? xcd * (q + 1) : r * (q + 1) + (xcd - r) * q) + sub;
    int bx = wgid % gx, by = wgid / gx;
    int bm = by * BM, bn = bx * 128;

    __shared__ short Als[NBUF][BM * 64];
    __shared__ short Bls[NBUF][128 * 64];
    int tid = threadIdx.x;
    int lane = tid & 63, wid = tid >> 6;
    int wm = wid >> 1, wn = wid & 1;

    int t3 = tid >> 3, t7 = tid & 7;
    const bf16* gA[AL];
    int aOff[AL];
    #pragma unroll
    for (int i = 0; i < AL; ++i) {
        int rA = i * 32 + t3;
        int kA = t7 ^ (rA & 7);
        gA[i] = A + (size_t)(bm + rA) * K + kA * 8;
        aOff[i] = (i * 256 + wid * 64) * 8;
    }
    const bf16* gB[4];
    int bOff[4];
    #pragma unroll
    for (int i = 0; i < 4; ++i) {
        int rB = i * 32 + t3;
        int kB = t7 ^ (rB & 7);
        gB[i] = Wt + (size_t)(bn + rB) * K + kB * 8;
        bOff[i] = (i * 256 + wid * 64) * 8;
    }

    auto stage = [&](int buf, int k0) {
        #pragma unroll
        for (int i = 0; i < AL; ++i) gload_lds16(gA[i] + k0, &Als[buf][aOff[i]]);
        #pragma unroll
        for (int i = 0; i < 4; ++i) gload_lds16(gB[i] + k0, &Bls[buf][bOff[i]]);
    };

    f32x4 acc[MI][4];
    #pragma unroll
    for (int i = 0; i < MI; ++i)
        #pragma unroll
        for (int j = 0; j < 4; ++j)
            acc[i][j] = (f32x4){0.f, 0.f, 0.f, 0.f};

    int nsteps = K >> 6;
    stage(0, 0);
    if (nsteps > 1) stage(1, 64);

    for (int s = 0; s < nsteps; ++s) {
        int buf = s % 3;
        if (s + 1 < nsteps) {
            asm volatile("s_waitcnt vmcnt(%0)" :: "n"(NL) : "memory");
        } else {
            asm volatile("s_waitcnt vmcnt(0)" ::: "memory");
        }
        __builtin_amdgcn_s_barrier();
        __builtin_amdgcn_sched_barrier(0);

        bf16x8 af[2][MI], bfr[2][4];
        #pragma unroll
        for (int kw = 0; kw < 2; ++kw) {
            int kc = kw * 4 + (lane >> 4);
            #pragma unroll
            for (int mi = 0; mi < MI; ++mi) {
                int row = wm * (BM / 2) + mi * 16 + (lane & 15);
                int kbp = kc ^ (row & 7);
                af[kw][mi] = *reinterpret_cast<const bf16x8*>(&Als[buf][row * 64 + kbp * 8]);
            }
            #pragma unroll
            for (int nj = 0; nj < 4; ++nj) {
                int row = wn * 64 + nj * 16 + (lane & 15);
                int kbp = kc ^ (row & 7);
                bfr[kw][nj] = *reinterpret_cast<const bf16x8*>(&Bls[buf][row * 64 + kbp * 8]);
            }
        }
        if (s + 2 < nsteps) stage((s + 2) % 3, (s + 2) * 64);

        __builtin_amdgcn_s_setprio(1);
        #pragma unroll
        for (int kw = 0; kw < 2; ++kw)
            #pragma unroll
            for (int mi = 0; mi < MI; ++mi)
                #pragma unroll
                for (int nj = 0; nj < 4; ++nj)
                    acc[mi][nj] = __builtin_amdgcn_mfma_f32_16x16x32_bf16(af[kw][mi], bfr[kw][nj], acc[mi][nj], 0, 0, 0);
        __builtin_amdgcn_s_setprio(0);

        __builtin_amdgcn_sched_barrier(0);
        __builtin_amdgcn_s_barrier();
    }

    #pragma unroll
    for (int mi = 0; mi < MI; ++mi) {
        #pragma unroll
        for (int nj = 0; nj < 4; ++nj) {
            int r0 = bm + wm * (BM / 2) + mi * 16 + ((lane >> 4) << 2);
            int col = bn + wn * 64 + nj * 16 + (lane & 15);
            if (col >= Nstore) continue;
            #pragma unroll
            for (int j = 0; j < 4; ++j) {
                int row = r0 + j;
                if (row >= M) continue;
                float v = acc[mi][nj][j];
                if (MODE == 4) {
                    if (col < 1024) {
                        float z = v + bias[col];
                        float sp = (z > 20.f) ? z : log1pf(__expf(z));
                        Cb[(size_t)row * 1024 + col] = __float2bfloat16(sp);
                    } else {
                        Cf2[(size_t)row * 32 + (col - 1024)] = v;
                    }
                } else {
                    size_t o = (size_t)row * ldc + col;
                    if (MODE == 0) Cb[o] = __float2bfloat16(v);
                    else if (MODE == 2) Cb[o] = __float2bfloat16(v + bias[col] + pos[(size_t)(row % L_SEQ) * D_MODEL + col]);
                    else if (MODE == 3) {
                        unsigned short hb = *reinterpret_cast<unsigned short*>(&Cb[o]);
                        Cb[o] = __float2bfloat16(bfbits2f(hb) + v);
                    }
                }
            }
        }
    }
}

// ---------------------------------------------------------------------------
// RMSNorm, wave-per-row: 4 rows/block, no barriers, shfl_xor reduce.  h bf16.
__global__ __launch_bounds__(256) void rmsnorm_kernel(
    const bf16* __restrict__ h, const float* __restrict__ w, bf16* __restrict__ o)
{
    int row = (blockIdx.x << 2) | (threadIdx.x >> 6);
    int lane = threadIdx.x & 63;
    short8 hv = *reinterpret_cast<const short8*>(h + (size_t)row * D_MODEL + lane * 8);
    float v[8];
    #pragma unroll
    for (int j = 0; j < 8; ++j) v[j] = bfbits2f(hv[j]);
    float ss = 0.f;
    #pragma unroll
    for (int j = 0; j < 8; ++j) ss += v[j] * v[j];
    #pragma unroll
    for (int off = 32; off; off >>= 1) ss += __shfl_xor(ss, off);
    float sc = rsqrtf(ss * (1.f / D_MODEL) + 1e-5f);
    const float* wr = w + lane * 8;
    f32x4 w0 = *reinterpret_cast<const f32x4*>(wr);
    f32x4 w1 = *reinterpret_cast<const f32x4*>(wr + 4);
    float wv[8] = {w0.x, w0.y, w0.z, w0.w, w1.x, w1.y, w1.z, w1.w};
    short8 ov;
    #pragma unroll
    for (int j = 0; j < 8; ++j) ov[j] = (short)f2bfbits(v[j] * sc * wv[j]);
    *reinterpret_cast<short8*>(o + (size_t)row * D_MODEL + lane * 8) = ov;
}

// causal depthwise conv (k=4) + SiLU + gate precompute, vectorized x8 channels.
__global__ __launch_bounds__(256) void conv_silu_kernel(
    const bf16* __restrict__ xr, const float* __restrict__ cwT,
    bf16* __restrict__ xs, unsigned int* __restrict__ ug)
{
    int idx = blockIdx.x * 256 + threadIdx.x;
    if (idx >= ROWS * 128) return;
    int dg = idx & 127, row = idx >> 7;
    int d0 = dg << 3;
    int l = row % L_SEQ;
    float acc[8] = {0.f,0.f,0.f,0.f,0.f,0.f,0.f,0.f};
    #pragma unroll
    for (int k = 0; k < 4; ++k) {
        int ls = l - 3 + k;
        if (ls < 0) continue;
        short8 xv = *reinterpret_cast<const short8*>(xr + (size_t)(row - 3 + k) * 2048 + d0);
        const float* wk = cwT + k * 1024 + d0;
        #pragma unroll
        for (int j = 0; j < 8; ++j)
            acc[j] += bfbits2f(xv[j]) * wk[j];
    }
    short8 rv = *reinterpret_cast<const short8*>(xr + (size_t)row * 2048 + 1024 + d0);
    short8 xsv;
    unsigned ugv[8];
    #pragma unroll
    for (int j = 0; j < 8; ++j) {
        float u = acc[j] / (1.f + __expf(-acc[j]));
        unsigned short ub = f2bfbits(u);
        xsv[j] = (short)ub;
        float res = bfbits2f(rv[j]);
        float g = res / (1.f + __expf(-res));
        ugv[j] = (unsigned)ub | ((unsigned)f2bfbits(g) << 16);
    }
    *reinterpret_cast<short8*>(xs + (size_t)row * 1024 + d0) = xsv;
    uint4* up = reinterpret_cast<uint4*>(ug + (size_t)row * 1024 + d0);
    up[0] = make_uint4(ugv[0], ugv[1], ugv[2], ugv[3]);
    up[1] = make_uint4(ugv[4], ugv[5], ugv[6], ugv[7]);
}

// ---------------------------------------------------------------------------
// State-parallel scan + gate: 4 states/lane, 4 lanes/channel, 64 ch/block.
__global__ __launch_bounds__(256) void scan_sp_kernel(
    const unsigned int* __restrict__ ug,   // {u,g} bf16x2  [rows,1024]
    const unsigned short* __restrict__ dl, // delta bf16    [rows,1024]
    const float* __restrict__ bc,          // [rows,32]  {B0,C0,B1,C1,...}
    const float* __restrict__ A_log,       // [1024,16]
    const float* __restrict__ Dv,          // [1024]
    bf16* __restrict__ y)                  // [rows,1024] bf16
{
    int tid = threadIdx.x;
    int n3 = tid & 3, ch = tid >> 2;
    int b = blockIdx.x >> 4;
    int d = (((int)blockIdx.x & 15) << 6) | ch;
    size_t bbase = (size_t)b * L_SEQ;

    const float L2E = 1.4426950408889634f;
    float A0 = -__expf(A_log[d * 16 + 4 * n3])     * L2E;
    float A1 = -__expf(A_log[d * 16 + 4 * n3 + 1]) * L2E;
    float A2 = -__expf(A_log[d * 16 + 4 * n3 + 2]) * L2E;
    float A3 = -__expf(A_log[d * 16 + 4 * n3 + 3]) * L2E;
    float Dd = Dv[d];
    float s0 = 0.f, s1 = 0.f, s2 = 0.f, s3 = 0.f;

    const unsigned* pu        = ug + bbase * 1024 + d;
    const unsigned short* pd  = dl + bbase * 1024 + d;
    const float*    pb = bc + bbase * 32 + 8 * n3;
    bf16*           py = y + bbase * 1024 + d;

    unsigned uv[8];
    unsigned short dv[8];
    f32x4 bc0[8], bc1[8];

#define LOADSLOT(i) { \
    uv[i]  = pu[(i) * 1024]; \
    dv[i]  = pd[(i) * 1024]; \
    bc0[i] = *reinterpret_cast<const f32x4*>(pb + (i) * 32); \
    bc1[i] = *reinterpret_cast<const f32x4*>(pb + (i) * 32 + 4); }

#define STEP(i) { \
    float _dl = bfbits2f(dv[i]); \
    float _u  = __int_as_float(uv[i] << 16); \
    float _a0 = __builtin_amdgcn_exp2f(_dl * A0); \
    float _a1 = __builtin_amdgcn_exp2f(_dl * A1); \
    float _a2 = __builtin_amdgcn_exp2f(_dl * A2); \
    float _a3 = __builtin_amdgcn_exp2f(_dl * A3); \
    float _du = _dl * _u; \
    s0 = _a0 * s0 + _du * bc0[i].x; \
    s1 = _a1 * s1 + _du * bc0[i].z; \
    s2 = _a2 * s2 + _du * bc1[i].x; \
    s3 = _a3 * s3 + _du * bc1[i].z; \
    float _p  = s0 * bc0[i].y + s1 * bc0[i].w; \
    float _p2 = s2 * bc1[i].y + s3 * bc1[i].w; \
    _p += _p2; \
    _p += __int_as_float(__builtin_amdgcn_mov_dpp(__float_as_int(_p), 0xB1, 0xF, 0xF, true)); \
    _p += __int_as_float(__builtin_amdgcn_mov_dpp(__float_as_int(_p), 0x4E, 0xF, 0xF, true)); \
    if (n3 == 0) { \
        float _g = __int_as_float(uv[i] & 0xFFFF0000u); \
        py[(i) * 1024] = __float2bfloat16((_p + _u * Dd) * _g); \
    } }

    LOADSLOT(0) LOADSLOT(1) LOADSLOT(2) LOADSLOT(3)
    LOADSLOT(4) LOADSLOT(5) LOADSLOT(6) LOADSLOT(7)
    pu += 8 * 1024; pd += 8 * 1024; pb += 8 * 32;

    for (int g = 0; g < 23; ++g) {
        STEP(0) LOADSLOT(0)
        STEP(1) LOADSLOT(1)
        STEP(2) LOADSLOT(2)
        STEP(3) LOADSLOT(3)
        STEP(4) LOADSLOT(4)
        STEP(5) LOADSLOT(5)
        STEP(6) LOADSLOT(6)
        STEP(7) LOADSLOT(7)
        pu += 8 * 1024; pd += 8 * 1024; pb += 8 * 32; py += 8 * 1024;
    }
    STEP(0) LOADSLOT(0)
    STEP(1) LOADSLOT(1)
    STEP(2) LOADSLOT(2)
    STEP(3) LOADSLOT(3)
    STEP(4) STEP(5) STEP(6) STEP(7)
    py += 8 * 1024;
    STEP(0) STEP(1) STEP(2) STEP(3)
#undef LOADSLOT
#undef STEP
}

// ---------------------------------------------------------------------------
// two-phase mean (h bf16).  Phase A: grid (8,16): block (q,b) sums a 25-row chunk.
__global__ __launch_bounds__(256) void mean_part_kernel(
    const bf16* __restrict__ h, float* __restrict__ hmp)
{
    int q = blockIdx.x, b = blockIdx.y;
    int l0 = q * 25;
    int l1 = min(l0 + 25, L_SEQ);
    const unsigned short* hb =
        reinterpret_cast<const unsigned short*>(h + ((size_t)b * L_SEQ + l0) * D_MODEL);
    #pragma unroll
    for (int half = 0; half < 2; ++half) {
        int c = threadIdx.x + half * 256;
        float acc = 0.f;
        const unsigned short* hp = hb + c;
        for (int l = l0; l < l1; ++l) {
            acc += bfbits2f(*hp);
            hp += D_MODEL;
        }
        hmp[((size_t)b * 8 + q) * D_MODEL + c] = acc;
    }
}

// head: phase B reduce 8 partials into LDS, then out[b][c].  grid (4,16)
__global__ __launch_bounds__(256) void head_kernel(
    const float* __restrict__ hmp, const float* __restrict__ head_w,
    const float* __restrict__ head_b, float* __restrict__ out)
{
    __shared__ float hmr[D_MODEL];
    int tid = threadIdx.x;
    int b = blockIdx.y;
    const float* hp = hmp + (size_t)b * 8 * D_MODEL;
    #pragma unroll
    for (int half = 0; half < 2; ++half) {
        int c = tid + half * 256;
        float acc = 0.f;
        #pragma unroll
        for (int q = 0; q < 8; ++q) acc += hp[q * D_MODEL + c];
        hmr[c] = acc * (1.f / L_SEQ);
    }
    __syncthreads();
    int c = blockIdx.x * 256 + tid;
    if (c >= N_CLASSES) return;
    float acc = head_b[c];
    #pragma unroll 8
    for (int k = 0; k < D_MODEL; ++k)
        acc += hmr[k] * head_w[(size_t)k * N_CLASSES + c];
    out[(size_t)b * N_CLASSES + c] = acc;
}

// ---------------------------------------------------------------------------
extern "C" void kernel_launch(void* const* d_in, const int* in_sizes, int n_in,
                              void* d_out, int out_size, void* d_ws, size_t ws_size,
                              hipStream_t stream) {
    const float* x         = (const float*)d_in[0];
    const float* patch_w   = (const float*)d_in[1];
    const float* patch_b   = (const float*)d_in[2];
    const float* norm_w    = (const float*)d_in[3];
    const float* in_proj_w = (const float*)d_in[4];
    const float* conv_w    = (const float*)d_in[5];
    const float* x_proj_w  = (const float*)d_in[6];
    const float* dt_proj_w = (const float*)d_in[7];
    const float* dt_proj_b = (const float*)d_in[8];
    const float* A_log     = (const float*)d_in[9];
    const float* Dv        = (const float*)d_in[10];
    const float* out_proj_w= (const float*)d_in[11];
    const float* head_w    = (const float*)d_in[12];
    const float* head_b    = (const float*)d_in[13];
    float* out = (float*)d_out;

    char* base = (char*)d_ws;
    size_t off = 0;
    auto alloc = [&](size_t bytes) -> void* {
        void* p = base + off;
        off += (bytes + 255) & ~(size_t)255;
        return p;
    };
    float* pos   = (float*)alloc((size_t)L_SEQ * D_MODEL * 4);
    bf16*  pwT   = (bf16*) alloc((size_t)D_MODEL * PATCH_DIM * 2);
    bf16*  inT   = (bf16*) alloc((size_t)N_LAYERS * 2 * D_INNER * D_MODEL * 2);
    bf16*  WtBig = (bf16*) alloc((size_t)N_LAYERS * NBIG * D_INNER * 2);
    bf16*  opT   = (bf16*) alloc((size_t)N_LAYERS * D_MODEL * D_INNER * 2);
    float* cwT   = (float*)alloc((size_t)N_LAYERS * 4 * D_INNER * 4);
    bf16*  h     = (bf16*) alloc((size_t)ROWSP * D_MODEL * 2);
    bf16*  xn    = (bf16*) alloc((size_t)ROWSP * D_MODEL * 2);
    char*  reg0  = (char*) alloc((size_t)ROWSP * 2 * D_INNER * 2);
    bf16*  p     = (bf16*)reg0;
    bf16*  xr    = (bf16*)reg0;
    bf16*  xs    = (bf16*) alloc((size_t)ROWSP * D_INNER * 2);
    unsigned int* ug = (unsigned int*)alloc((size_t)ROWSP * D_INNER * 4);
    bf16*  delta = (bf16*) alloc((size_t)ROWSP * D_INNER * 2);
    float* bcb   = (float*)alloc((size_t)ROWS * 32 * 4);
    bf16*  yb    = (bf16*) alloc((size_t)ROWSP * D_INNER * 2);
    float* hmp   = (float*)alloc((size_t)BATCH * 8 * D_MODEL * 4);

    // ---- prologue + batched weight prep ----
    patchify_kernel<<<ROWS, 256, 0, stream>>>(x, p);
    smallprep_kernel<<<968, 256, 0, stream>>>(pos, x_proj_w, WtBig, conv_w, cwT);
    transpose_bf16_kernel<<<dim3(16, 24), 256, 0, stream>>>(
        patch_w, pwT, PATCH_DIM, D_MODEL, D_MODEL, 0, 0);
    transpose_bf16_kernel<<<dim3(64, 16, N_LAYERS), 256, 0, stream>>>(
        in_proj_w, inT, D_MODEL, 2 * D_INNER, 2 * D_INNER,
        (size_t)D_MODEL * 2 * D_INNER, (size_t)2 * D_INNER * D_MODEL);
    transpose_bf16_kernel<<<dim3(16, 32, N_LAYERS), 256, 0, stream>>>(
        out_proj_w, opT, D_INNER, D_MODEL, D_MODEL,
        (size_t)D_INNER * D_MODEL, (size_t)D_MODEL * D_INNER);
    wcomb_kernel<<<dim3(32, 32, N_LAYERS), 256, 0, stream>>>(
        x_proj_w, dt_proj_w, WtBig);

    // h = bf16(p @ patch_w + patch_b + pos)   (BM=32, grid 400)
    gemm64<2, 32><<<(D_MODEL / 128) * (ROWSP / 32), 256, 0, stream>>>(
        p, pwT, PATCH_DIM, D_MODEL / 128, D_MODEL, ROWS, D_MODEL,
        nullptr, h, patch_b, pos, nullptr);

    for (int layer = 0; layer < N_LAYERS; ++layer) {
        rmsnorm_kernel<<<ROWS / 4, 256, 0, stream>>>(h, norm_w + layer * D_MODEL, xn);

        // xr = xn @ in_proj  [3136,2048] bf16   (BM=64, grid 800)
        gemm64<0, 64><<<(2 * D_INNER / 128) * (ROWSP / 64), 256, 0, stream>>>(
            xn, inT + (size_t)layer * 2 * D_INNER * D_MODEL,
            D_MODEL, 2 * D_INNER / 128, 2 * D_INNER, ROWS, 2 * D_INNER,
            nullptr, xr, nullptr, nullptr, nullptr);

        conv_silu_kernel<<<(ROWS * 128 + 255) / 256, 256, 0, stream>>>(
            xr, cwT + (size_t)layer * 4 * D_INNER, xs, ug);

        // delta(bf16) = softplus(xs @ W_comb + dtb); bc interleaved  (BM=64, grid 450)
        gemm64<4, 64><<<(NBIG / 128) * (ROWSP / 64), 256, 0, stream>>>(
            xs, WtBig + (size_t)layer * NBIG * D_INNER,
            D_INNER, NBIG / 128, 1056, ROWS, 0,
            nullptr, delta, dt_proj_b + (size_t)layer * D_INNER, nullptr, bcb);

        // state-parallel scan + gate -> yb bf16  (grid 256)
        scan_sp_kernel<<<BATCH * (D_INNER / 64), 256, 0, stream>>>(
            ug, (const unsigned short*)delta, bcb,
            A_log + (size_t)layer * D_INNER * D_STATE,
            Dv + (size_t)layer * D_INNER, yb);

        // h += yb @ out_proj (bf16 RMW)   (BM=32, grid 400)
        gemm64<3, 32><<<(D_MODEL / 128) * (ROWSP / 32), 256, 0, stream>>>(
            yb, opT + (size_t)layer * D_MODEL * D_INNER,
            D_INNER, D_MODEL / 128, D_MODEL, ROWS, D_MODEL,
            nullptr, h, nullptr, nullptr, nullptr);
    }

    mean_part_kernel<<<dim3(8, BATCH), 256, 0, stream>>>(h, hmp);
    head_kernel<<<dim3(4, BATCH), 256, 0, stream>>>(hmp, head_w, head_b, out);
}